// Round 1
// baseline (305.780 us; speedup 1.0000x reference)
//
#include <hip/hip_runtime.h>
#include <math.h>

#define NB 512
#define MODES 1000
#define LL 64
#define PI_D 3.14159265358979323846

// ws layout (bytes)
#define OFF_PART   0          // double2[192] per-(k,m) weight row sums
#define OFF_SCAL   4096       // double[4]: c0re,c0im,c1re,c1im
#define OFF_T2RE   4224       // double[64]
#define OFF_T2IM   4736       // double[64]
#define OFF_GP     5248       // float[64]  g(+1)
#define OFF_CNT    5504       // int irregular count
#define OFF_W2T    16384      // float[64000]  W2 transposed [o][j]
#define OFF_SGN    524288     // float[512000] sign of s2
#define OFF_S2     2621440    // float[512000] s2 value
#define OFF_IRR    4718592    // int[512000] irregular indices
#define OFF_E      6815744    // float[1000*1024] E[o][f]
#define OFF_HPRE   11010048   // float[512*1024] pre-activation h

__device__ __forceinline__ double retanh_d(double a, double b) {
    // Re(tanh(a+ib)) = sinh(2a)/(cosh(2a)+cos(2b)), stable for large |a|
    if (fabs(a) > 20.0) return a > 0.0 ? 1.0 : -1.0;
    double e2 = exp(2.0 * a);
    double em2 = 1.0 / e2;
    return (e2 - em2) / (e2 + em2 + 2.0 * cos(2.0 * b));
}

// Per-(weight k, row m) sums of re/im over the 1000 columns.
__global__ void k_sumw(const float* __restrict__ w0r, const float* __restrict__ w0i,
                       const float* __restrict__ w1r, const float* __restrict__ w1i,
                       const float* __restrict__ w2r, const float* __restrict__ w2i,
                       char* ws) {
    int m = blockIdx.x, k = blockIdx.y, t = threadIdx.x;
    const float* wr = (k == 0) ? w0r : (k == 1) ? w1r : w2r;
    const float* wi = (k == 0) ? w0i : (k == 1) ? w1i : w2i;
    double sr = 0.0, si = 0.0;
    for (int c = t; c < MODES; c += 256) {
        sr += (double)wr[m * MODES + c];
        si += (double)wi[m * MODES + c];
    }
    __shared__ double lr[256], li[256];
    lr[t] = sr; li[t] = si; __syncthreads();
    for (int s = 128; s > 0; s >>= 1) {
        if (t < s) { lr[t] += lr[t + s]; li[t] += li[t + s]; }
        __syncthreads();
    }
    if (t == 0) {
        double2* p = (double2*)(ws + OFF_PART);
        p[k * 64 + m] = make_double2(lr[0], li[0]);
    }
}

// c0, c1 totals; T2[j] via 64-point inverse DFT of row sums; gp = g(+1); reset counter.
__global__ void k_prep(char* ws) {
    int t = threadIdx.x; // 64 threads
    double2* part = (double2*)(ws + OFF_PART);
    double* scal  = (double*)(ws + OFF_SCAL);
    double* t2re  = (double*)(ws + OFF_T2RE);
    double* t2im  = (double*)(ws + OFF_T2IM);
    float*  gp    = (float*)(ws + OFF_GP);
    __shared__ double ar[64], ai[64];
    for (int k = 0; k < 2; ++k) {
        double2 v = part[k * 64 + t];
        ar[t] = v.x; ai[t] = v.y; __syncthreads();
        for (int s = 32; s > 0; s >>= 1) {
            if (t < s) { ar[t] += ar[t + s]; ai[t] += ai[t + s]; }
            __syncthreads();
        }
        if (t == 0) { scal[2 * k] = ar[0]; scal[2 * k + 1] = ai[0]; }
        __syncthreads();
    }
    __shared__ double sre[64], sim[64];
    double2 v = part[128 + t];
    sre[t] = v.x; sim[t] = v.y; __syncthreads();
    double tr = 0.0, ti = 0.0;
    for (int m = 0; m < 64; ++m) {
        int r = (t * m) & 63;                  // exact angle reduction
        double th = (double)r * (PI_D / 32.0); // 2*pi*r/64
        double c = cos(th), s = sin(th);
        tr += sre[m] * c - sim[m] * s;
        ti += sre[m] * s + sim[m] * c;
    }
    t2re[t] = tr; t2im[t] = ti;
    gp[t] = (float)retanh_d(tr, ti);
    if (t == 0) *(int*)(ws + OFF_CNT) = 0;
}

// W2 transpose: W2t[o*64+j] = W2[j*1000+o]
__global__ void k_w2t(const float* __restrict__ w2, char* ws) {
    int idx = blockIdx.x * 256 + threadIdx.x;
    if (idx < 64 * MODES) {
        int o = idx >> 6, j = idx & 63;
        ((float*)(ws + OFF_W2T))[idx] = w2[j * MODES + o];
    }
}

// s2 per (b,f) + sign classification + irregular list
__global__ void k_s(const float* __restrict__ params, char* ws) {
    int idx = blockIdx.x * 256 + threadIdx.x; // 512000 total
    const double* scal = (const double*)(ws + OFF_SCAL);
    double c0r = scal[0], c0i = scal[1], c1r = scal[2], c1i = scal[3];
    float p0 = params[(size_t)idx * 64];
    double s1 = retanh_d((double)p0 * c0r, (double)p0 * c0i);
    float s1f = (float)s1;
    double s2 = retanh_d((double)s1f * c1r, (double)s1f * c1i);
    float s2f = (float)s2;
    float sg; bool irr = false;
    if (s2f == 1.0f)       sg = 1.0f;
    else if (s2f == -1.0f) sg = -1.0f;
    else { sg = (s2f >= 0.0f) ? 1.0f : -1.0f; irr = true; }
    ((float*)(ws + OFF_SGN))[idx] = sg;
    ((float*)(ws + OFF_S2))[idx] = s2f;
    if (irr) {
        int pos = atomicAdd((int*)(ws + OFF_CNT), 1);
        ((int*)(ws + OFF_IRR))[pos] = idx;
    }
}

// E[o][f] = sum_j gp[j] * W1[o, 64f+j]  — the single full read of W1 (256 MB)
__global__ void k_E(const float* __restrict__ w1, char* ws) {
    int o = blockIdx.y;
    int f = blockIdx.x * 256 + threadIdx.x;
    __shared__ float4 g4[16];
    if (threadIdx.x < 16) g4[threadIdx.x] = ((const float4*)(ws + OFF_GP))[threadIdx.x];
    __syncthreads();
    if (f >= MODES) return;
    const float4* w4 = (const float4*)w1;
    size_t base = (size_t)o * 16000 + (size_t)f * 16;
    float acc = 0.0f;
#pragma unroll
    for (int r = 0; r < 16; ++r) {
        float4 w = w4[base + r];
        float4 g = g4[r];
        acc += w.x * g.x + w.y * g.y + w.z * g.z + w.w * g.w;
    }
    ((float*)(ws + OFF_E))[o * 1024 + f] = acc;
}

// h_pre[b,o] = b1[o] + sum_f sgn[b,f] * E[o,f]   (512x1000x1000 fp32 GEMM)
__global__ void k_gemm5(const float* __restrict__ b1, char* ws) {
    __shared__ float As[64][33]; // sgn tile [b][f]
    __shared__ float Bs[64][33]; // E tile [o][f]
    const float* sgn = (const float*)(ws + OFF_SGN);
    const float* E   = (const float*)(ws + OFF_E);
    float* hpre      = (float*)(ws + OFF_HPRE);
    int bx = blockIdx.x;              // o-tile (16)
    int by = blockIdx.y;              // b-tile (8)
    int tx = threadIdx.x, ty = threadIdx.y;
    int t = ty * 16 + tx;
    float acc[4][4] = {};
    for (int kt = 0; kt < 32; ++kt) {
        int f0 = kt * 32;
        for (int r = 0; r < 8; ++r) {
            int e = r * 256 + t;
            int row = e >> 5, col = e & 31;
            int f = f0 + col;
            As[row][col] = (f < MODES) ? sgn[(by * 64 + row) * MODES + f] : 0.0f;
            int oo = bx * 64 + row;
            Bs[row][col] = (f < MODES && oo < MODES) ? E[oo * 1024 + f] : 0.0f;
        }
        __syncthreads();
        for (int kk = 0; kk < 32; ++kk) {
            float av[4], bv[4];
#pragma unroll
            for (int i = 0; i < 4; ++i) av[i] = As[ty * 4 + i][kk];
#pragma unroll
            for (int j = 0; j < 4; ++j) bv[j] = Bs[tx * 4 + j][kk];
#pragma unroll
            for (int i = 0; i < 4; ++i)
#pragma unroll
                for (int j = 0; j < 4; ++j) acc[i][j] += av[i] * bv[j];
        }
        __syncthreads();
    }
    for (int i = 0; i < 4; ++i) {
        int b = by * 64 + ty * 4 + i;
        for (int j = 0; j < 4; ++j) {
            int o = bx * 64 + tx * 4 + j;
            if (o < MODES) hpre[b * 1024 + o] = acc[i][j] + b1[o];
        }
    }
}

// Exact patch for (b,f) where s2 != +/-1: hpre[b,:] += (g(s2) - sgn*gp) . W1[:, 64f:64f+64]
__global__ void k_corr(const float* __restrict__ w1, char* ws) {
    const int t = threadIdx.x;
    int cnt = *(const int*)(ws + OFF_CNT);
    const int* irr    = (const int*)(ws + OFF_IRR);
    const float* s2a  = (const float*)(ws + OFF_S2);
    const float* sgn  = (const float*)(ws + OFF_SGN);
    const double* t2re = (const double*)(ws + OFF_T2RE);
    const double* t2im = (const double*)(ws + OFF_T2IM);
    const float* gp   = (const float*)(ws + OFF_GP);
    float* hpre       = (float*)(ws + OFF_HPRE);
    __shared__ __align__(16) float cv[64];
    for (int e = blockIdx.x; e < cnt; e += gridDim.x) {
        int idx = irr[e];
        int b = idx / MODES, f = idx % MODES;
        float s2 = s2a[idx], sg = sgn[idx];
        __syncthreads();
        if (t < 64) {
            double g = retanh_d((double)s2 * t2re[t], (double)s2 * t2im[t]);
            cv[t] = (float)g - sg * gp[t];
        }
        __syncthreads();
        const float4* w4 = (const float4*)w1;
        const float4* c4 = (const float4*)cv;
        for (int o = t; o < MODES; o += 256) {
            size_t base = (size_t)o * 16000 + (size_t)f * 16;
            float acc = 0.0f;
#pragma unroll
            for (int r = 0; r < 16; ++r) {
                float4 w = w4[base + r];
                float4 c = c4[r];
                acc += w.x * c.x + w.y * c.y + w.z * c.z + w.w * c.w;
            }
            atomicAdd(&hpre[b * 1024 + o], acc);
        }
    }
}

// out[b,j] = sigmoid(b2[j] + sum_o tanh(hpre[b,o]) * W2t[o][j])
__global__ void k_final(const float* __restrict__ b2, float* __restrict__ out, char* ws) {
    int b = blockIdx.x, t = threadIdx.x;
    const float* hpre = (const float*)(ws + OFF_HPRE);
    const float* w2t  = (const float*)(ws + OFF_W2T);
    __shared__ float th[MODES];
    __shared__ float part[4][64];
    for (int o = t; o < MODES; o += 256) th[o] = tanhf(hpre[b * 1024 + o]);
    __syncthreads();
    int j = t & 63, c = t >> 6;
    float acc = 0.0f;
    for (int o = c * 250; o < c * 250 + 250; ++o) acc += th[o] * w2t[o * 64 + j];
    part[c][j] = acc;
    __syncthreads();
    if (t < 64) {
        float s = part[0][t] + part[1][t] + part[2][t] + part[3][t] + b2[t];
        out[b * 64 + t] = 1.0f / (1.0f + expf(-s));
    }
}

extern "C" void kernel_launch(void* const* d_in, const int* in_sizes, int n_in,
                              void* d_out, int out_size, void* d_ws, size_t ws_size,
                              hipStream_t stream) {
    const float* params = (const float*)d_in[0];
    const float* w0r = (const float*)d_in[1];
    const float* w0i = (const float*)d_in[2];
    const float* w1r = (const float*)d_in[3];
    const float* w1i = (const float*)d_in[4];
    const float* w2r = (const float*)d_in[5];
    const float* w2i = (const float*)d_in[6];
    const float* lin1w = (const float*)d_in[7];
    const float* lin1b = (const float*)d_in[8];
    const float* lin2w = (const float*)d_in[9];
    const float* lin2b = (const float*)d_in[10];
    char* ws = (char*)d_ws;
    float* out = (float*)d_out;

    k_sumw<<<dim3(64, 3), 256, 0, stream>>>(w0r, w0i, w1r, w1i, w2r, w2i, ws);
    k_prep<<<1, 64, 0, stream>>>(ws);
    k_w2t<<<250, 256, 0, stream>>>(lin2w, ws);
    k_s<<<2000, 256, 0, stream>>>(params, ws);
    k_E<<<dim3(4, 1000), 256, 0, stream>>>(lin1w, ws);
    k_gemm5<<<dim3(16, 8), dim3(16, 16), 0, stream>>>(lin1b, ws);
    k_corr<<<128, 256, 0, stream>>>(lin1w, ws);
    k_final<<<512, 256, 0, stream>>>(lin2b, out, ws);
}

// Round 2
// 177.421 us; speedup vs baseline: 1.7235x; 1.7235x over previous
//
#include <hip/hip_runtime.h>
#include <math.h>

#define NB 512
#define MODES 1000
#define LL 64
#define PI_D 3.14159265358979323846

// ws layout (bytes)
#define OFF_PART   0          // double2[192] per-(k,m) weight row sums
#define OFF_SCAL   4096       // double[4]: c0re,c0im,c1re,c1im
#define OFF_T2RE   4224       // double[64]
#define OFF_T2IM   4736       // double[64]
#define OFF_GP     5248       // float[64]  g(+1)
#define OFF_CNT    5504       // int irregular count
#define OFF_W2T    16384      // float[64000]  W2 transposed [o][j]
#define OFF_SGN    524288     // float[512000] sign of s2  [b][f]
#define OFF_S2     2621440    // float[512000] s2 value
#define OFF_IRR    4718592    // int[512000] irregular indices
#define OFF_E      6815744    // float[1000*1024] E[o][f]
#define OFF_HPRE   11010048   // float[512*1024] pre-activation h
#define OFF_SGNT   13107200   // float[1024*512]  sgn transposed [f][b], zero-padded f>=1000
#define OFF_ET     15204352   // float[1024*1024] E transposed [f][o], zero-padded

__device__ __forceinline__ double retanh_d(double a, double b) {
    // Re(tanh(a+ib)) = sinh(2a)/(cosh(2a)+cos(2b)), stable for large |a|
    if (fabs(a) > 20.0) return a > 0.0 ? 1.0 : -1.0;
    double e2 = exp(2.0 * a);
    double em2 = 1.0 / e2;
    return (e2 - em2) / (e2 + em2 + 2.0 * cos(2.0 * b));
}

// Per-(weight k, row m) sums of re/im over the 1000 columns.
__global__ void k_sumw(const float* __restrict__ w0r, const float* __restrict__ w0i,
                       const float* __restrict__ w1r, const float* __restrict__ w1i,
                       const float* __restrict__ w2r, const float* __restrict__ w2i,
                       char* ws) {
    int m = blockIdx.x, k = blockIdx.y, t = threadIdx.x;
    const float* wr = (k == 0) ? w0r : (k == 1) ? w1r : w2r;
    const float* wi = (k == 0) ? w0i : (k == 1) ? w1i : w2i;
    double sr = 0.0, si = 0.0;
    for (int c = t; c < MODES; c += 256) {
        sr += (double)wr[m * MODES + c];
        si += (double)wi[m * MODES + c];
    }
    __shared__ double lr[256], li[256];
    lr[t] = sr; li[t] = si; __syncthreads();
    for (int s = 128; s > 0; s >>= 1) {
        if (t < s) { lr[t] += lr[t + s]; li[t] += li[t + s]; }
        __syncthreads();
    }
    if (t == 0) {
        double2* p = (double2*)(ws + OFF_PART);
        p[k * 64 + m] = make_double2(lr[0], li[0]);
    }
}

// c0, c1 totals; T2[j] via 64-point inverse DFT of row sums; gp = g(+1); reset counter.
__global__ void k_prep(char* ws) {
    int t = threadIdx.x; // 64 threads
    double2* part = (double2*)(ws + OFF_PART);
    double* scal  = (double*)(ws + OFF_SCAL);
    double* t2re  = (double*)(ws + OFF_T2RE);
    double* t2im  = (double*)(ws + OFF_T2IM);
    float*  gp    = (float*)(ws + OFF_GP);
    __shared__ double ar[64], ai[64];
    for (int k = 0; k < 2; ++k) {
        double2 v = part[k * 64 + t];
        ar[t] = v.x; ai[t] = v.y; __syncthreads();
        for (int s = 32; s > 0; s >>= 1) {
            if (t < s) { ar[t] += ar[t + s]; ai[t] += ai[t + s]; }
            __syncthreads();
        }
        if (t == 0) { scal[2 * k] = ar[0]; scal[2 * k + 1] = ai[0]; }
        __syncthreads();
    }
    __shared__ double sre[64], sim[64];
    double2 v = part[128 + t];
    sre[t] = v.x; sim[t] = v.y; __syncthreads();
    double tr = 0.0, ti = 0.0;
    for (int m = 0; m < 64; ++m) {
        int r = (t * m) & 63;                  // exact angle reduction
        double th = (double)r * (PI_D / 32.0); // 2*pi*r/64
        double c = cos(th), s = sin(th);
        tr += sre[m] * c - sim[m] * s;
        ti += sre[m] * s + sim[m] * c;
    }
    t2re[t] = tr; t2im[t] = ti;
    gp[t] = (float)retanh_d(tr, ti);
    if (t == 0) *(int*)(ws + OFF_CNT) = 0;
}

// W2 transpose: W2t[o*64+j] = W2[j*1000+o]
__global__ void k_w2t(const float* __restrict__ w2, char* ws) {
    int idx = blockIdx.x * 256 + threadIdx.x;
    if (idx < 64 * MODES) {
        int o = idx >> 6, j = idx & 63;
        ((float*)(ws + OFF_W2T))[idx] = w2[j * MODES + o];
    }
}

// s2 per (b,f) + sign classification + irregular list
__global__ void k_s(const float* __restrict__ params, char* ws) {
    int idx = blockIdx.x * 256 + threadIdx.x; // 512000 total
    const double* scal = (const double*)(ws + OFF_SCAL);
    double c0r = scal[0], c0i = scal[1], c1r = scal[2], c1i = scal[3];
    float p0 = params[(size_t)idx * 64];
    double s1 = retanh_d((double)p0 * c0r, (double)p0 * c0i);
    float s1f = (float)s1;
    double s2 = retanh_d((double)s1f * c1r, (double)s1f * c1i);
    float s2f = (float)s2;
    float sg; bool irr = false;
    if (s2f == 1.0f)       sg = 1.0f;
    else if (s2f == -1.0f) sg = -1.0f;
    else { sg = (s2f >= 0.0f) ? 1.0f : -1.0f; irr = true; }
    ((float*)(ws + OFF_SGN))[idx] = sg;
    ((float*)(ws + OFF_S2))[idx] = s2f;
    if (irr) {
        int pos = atomicAdd((int*)(ws + OFF_CNT), 1);
        ((int*)(ws + OFF_IRR))[pos] = idx;
    }
}

// E[o][f] = sum_j gp[j] * W1[o, 64f+j]  — the single full read of W1 (256 MB)
__global__ void k_E(const float* __restrict__ w1, char* ws) {
    int o = blockIdx.y;
    int f = blockIdx.x * 256 + threadIdx.x;
    __shared__ float4 g4[16];
    if (threadIdx.x < 16) g4[threadIdx.x] = ((const float4*)(ws + OFF_GP))[threadIdx.x];
    __syncthreads();
    if (f >= MODES) return;
    const float4* w4 = (const float4*)w1;
    size_t base = (size_t)o * 16000 + (size_t)f * 16;
    float acc = 0.0f;
#pragma unroll
    for (int r = 0; r < 16; ++r) {
        float4 w = w4[base + r];
        float4 g = g4[r];
        acc += w.x * g.x + w.y * g.y + w.z * g.z + w.w * g.w;
    }
    ((float*)(ws + OFF_E))[o * 1024 + f] = acc;
}

// Transpose sgn [512][1000] -> sgnT [1024][512], zero-pad f>=1000
__global__ void k_trS(char* ws) {
    __shared__ float tile[32][33];
    const float* sgn = (const float*)(ws + OFF_SGN);
    float* sgnT = (float*)(ws + OFF_SGNT);
    int f0 = blockIdx.x * 32, b0 = blockIdx.y * 32;
    int tx = threadIdx.x, ty = threadIdx.y;
#pragma unroll
    for (int i = 0; i < 4; ++i) {
        int b = b0 + ty + i * 8;
        int f = f0 + tx;
        tile[ty + i * 8][tx] = (f < MODES) ? sgn[(size_t)b * MODES + f] : 0.0f;
    }
    __syncthreads();
#pragma unroll
    for (int i = 0; i < 4; ++i) {
        int f = f0 + ty + i * 8;
        int b = b0 + tx;
        sgnT[(size_t)f * 512 + b] = tile[tx][ty + i * 8];
    }
}

// Transpose E [1000][1024] -> ET [1024][1024], zero-pad both dims
__global__ void k_trE(char* ws) {
    __shared__ float tile[32][33];
    const float* E = (const float*)(ws + OFF_E);
    float* ET = (float*)(ws + OFF_ET);
    int f0 = blockIdx.x * 32, o0 = blockIdx.y * 32;
    int tx = threadIdx.x, ty = threadIdx.y;
#pragma unroll
    for (int i = 0; i < 4; ++i) {
        int o = o0 + ty + i * 8;
        int f = f0 + tx;
        tile[ty + i * 8][tx] = (o < MODES && f < MODES) ? E[(size_t)o * 1024 + f] : 0.0f;
    }
    __syncthreads();
#pragma unroll
    for (int i = 0; i < 4; ++i) {
        int f = f0 + ty + i * 8;
        int o = o0 + tx;
        ET[(size_t)f * 1024 + o] = tile[tx][ty + i * 8];
    }
}

// hpre[b][o] = b1[o] (o<1000) else 0
__global__ void k_init(const float* __restrict__ b1, char* ws) {
    int idx = blockIdx.x * 256 + threadIdx.x; // 512*1024
    int o = idx & 1023;
    ((float*)(ws + OFF_HPRE))[idx] = (o < MODES) ? b1[o] : 0.0f;
}

// hpre[b,o] += sum_f sgnT[f][b] * ET[f][o]  — split-K x4, atomic epilogue
__global__ void k_gemm(char* ws) {
    __shared__ float As[32][64]; // [kk][b]
    __shared__ float Bs[32][64]; // [kk][o]
    const float* sgnT = (const float*)(ws + OFF_SGNT);
    const float* ET   = (const float*)(ws + OFF_ET);
    float* hpre       = (float*)(ws + OFF_HPRE);
    int bx = blockIdx.x;  // o-tile 0..15
    int by = blockIdx.y;  // b-tile 0..7
    int bz = blockIdx.z;  // split 0..3
    int t = threadIdx.x;  // 256
    int tx = t & 15, ty = t >> 4;
    float acc[4][4] = {};
    int f0base = bz * 256;
    for (int kt = 0; kt < 8; ++kt) {
        int f0 = f0base + kt * 32;
        const float4* srcA = (const float4*)(sgnT + (size_t)f0 * 512 + by * 64);
        const float4* srcB = (const float4*)(ET + (size_t)f0 * 1024 + bx * 64);
        float4* dstA = (float4*)As;
        float4* dstB = (float4*)Bs;
#pragma unroll
        for (int i = 0; i < 2; ++i) {
            int ee = t + i * 256;           // 512 float4 elems per tile
            int row = ee >> 4, col4 = ee & 15;
            dstA[row * 16 + col4] = srcA[(size_t)row * 128 + col4];
            dstB[row * 16 + col4] = srcB[(size_t)row * 256 + col4];
        }
        __syncthreads();
#pragma unroll
        for (int kk = 0; kk < 32; ++kk) {
            float4 a4 = *(const float4*)&As[kk][ty * 4];
            float4 b4 = *(const float4*)&Bs[kk][tx * 4];
            float av[4] = {a4.x, a4.y, a4.z, a4.w};
            float bv[4] = {b4.x, b4.y, b4.z, b4.w};
#pragma unroll
            for (int i = 0; i < 4; ++i)
#pragma unroll
                for (int j = 0; j < 4; ++j) acc[i][j] += av[i] * bv[j];
        }
        __syncthreads();
    }
#pragma unroll
    for (int i = 0; i < 4; ++i) {
        int b = by * 64 + ty * 4 + i;
#pragma unroll
        for (int j = 0; j < 4; ++j) {
            int o = bx * 64 + tx * 4 + j;
            if (o < MODES) atomicAdd(&hpre[(size_t)b * 1024 + o], acc[i][j]);
        }
    }
}

// Exact patch for (b,f) where s2 != +/-1: hpre[b,:] += (g(s2) - sgn*gp) . W1[:, 64f:64f+64]
__global__ void k_corr(const float* __restrict__ w1, char* ws) {
    const int t = threadIdx.x;
    int cnt = *(const int*)(ws + OFF_CNT);
    const int* irr    = (const int*)(ws + OFF_IRR);
    const float* s2a  = (const float*)(ws + OFF_S2);
    const float* sgn  = (const float*)(ws + OFF_SGN);
    const double* t2re = (const double*)(ws + OFF_T2RE);
    const double* t2im = (const double*)(ws + OFF_T2IM);
    const float* gp   = (const float*)(ws + OFF_GP);
    float* hpre       = (float*)(ws + OFF_HPRE);
    __shared__ __align__(16) float cv[64];
    for (int e = blockIdx.x; e < cnt; e += gridDim.x) {
        int idx = irr[e];
        int b = idx / MODES, f = idx % MODES;
        float s2 = s2a[idx], sg = sgn[idx];
        __syncthreads();
        if (t < 64) {
            double g = retanh_d((double)s2 * t2re[t], (double)s2 * t2im[t]);
            cv[t] = (float)g - sg * gp[t];
        }
        __syncthreads();
        const float4* w4 = (const float4*)w1;
        const float4* c4 = (const float4*)cv;
        for (int o = t; o < MODES; o += 256) {
            size_t base = (size_t)o * 16000 + (size_t)f * 16;
            float acc = 0.0f;
#pragma unroll
            for (int r = 0; r < 16; ++r) {
                float4 w = w4[base + r];
                float4 c = c4[r];
                acc += w.x * c.x + w.y * c.y + w.z * c.z + w.w * c.w;
            }
            atomicAdd(&hpre[(size_t)b * 1024 + o], acc);
        }
    }
}

// out[b,j] = sigmoid(b2[j] + sum_o tanh(hpre[b,o]) * W2t[o][j])
__global__ void k_final(const float* __restrict__ b2, float* __restrict__ out, char* ws) {
    int b = blockIdx.x, t = threadIdx.x;
    const float* hpre = (const float*)(ws + OFF_HPRE);
    const float* w2t  = (const float*)(ws + OFF_W2T);
    __shared__ float th[MODES];
    __shared__ float part[4][64];
    for (int o = t; o < MODES; o += 256) th[o] = tanhf(hpre[(size_t)b * 1024 + o]);
    __syncthreads();
    int j = t & 63, c = t >> 6;
    float acc = 0.0f;
    for (int o = c * 250; o < c * 250 + 250; ++o) acc += th[o] * w2t[o * 64 + j];
    part[c][j] = acc;
    __syncthreads();
    if (t < 64) {
        float s = part[0][t] + part[1][t] + part[2][t] + part[3][t] + b2[t];
        out[b * 64 + t] = 1.0f / (1.0f + expf(-s));
    }
}

extern "C" void kernel_launch(void* const* d_in, const int* in_sizes, int n_in,
                              void* d_out, int out_size, void* d_ws, size_t ws_size,
                              hipStream_t stream) {
    const float* params = (const float*)d_in[0];
    const float* w0r = (const float*)d_in[1];
    const float* w0i = (const float*)d_in[2];
    const float* w1r = (const float*)d_in[3];
    const float* w1i = (const float*)d_in[4];
    const float* w2r = (const float*)d_in[5];
    const float* w2i = (const float*)d_in[6];
    const float* lin1w = (const float*)d_in[7];
    const float* lin1b = (const float*)d_in[8];
    const float* lin2w = (const float*)d_in[9];
    const float* lin2b = (const float*)d_in[10];
    char* ws = (char*)d_ws;
    float* out = (float*)d_out;

    k_sumw<<<dim3(64, 3), 256, 0, stream>>>(w0r, w0i, w1r, w1i, w2r, w2i, ws);
    k_prep<<<1, 64, 0, stream>>>(ws);
    k_w2t<<<250, 256, 0, stream>>>(lin2w, ws);
    k_s<<<2000, 256, 0, stream>>>(params, ws);
    k_trS<<<dim3(32, 16), dim3(32, 8), 0, stream>>>(ws);
    k_E<<<dim3(4, 1000), 256, 0, stream>>>(lin1w, ws);
    k_trE<<<dim3(32, 32), dim3(32, 8), 0, stream>>>(ws);
    k_init<<<2048, 256, 0, stream>>>(lin1b, ws);
    k_gemm<<<dim3(16, 8, 4), 256, 0, stream>>>(ws);
    k_corr<<<128, 256, 0, stream>>>(lin1w, ws);
    k_final<<<512, 256, 0, stream>>>(lin2b, out, ws);
}

// Round 3
// 137.472 us; speedup vs baseline: 2.2243x; 1.2906x over previous
//
#include <hip/hip_runtime.h>
#include <math.h>

#define NB 512
#define MODES 1000
#define LL 64
#define PI_D 3.14159265358979323846

// ws layout (bytes)
#define OFF_PART   0          // double2[192] per-(k,m) weight row sums
#define OFF_SCAL   4096       // double[4]: c0re,c0im,c1re,c1im
#define OFF_T2RE   4224       // double[64]
#define OFF_T2IM   4736       // double[64]
#define OFF_GP     5248       // float[64]  g(+1)
#define OFF_CNT    5504       // int irregular count
#define OFF_W2T    16384      // float[64000]  W2 transposed [o][j]
#define OFF_SGN    524288     // float[512000] sign of s2  [b][f]
#define OFF_S2     2621440    // float[512000] s2 value
#define OFF_IRR    4718592    // int[512000] irregular indices
#define OFF_E      6815744    // float[1000*1024] E[o][f]
#define OFF_SGNT   13107200   // float[1024*512]  sgn transposed [f][b], zero-padded
#define OFF_ET     15204352   // float[1024*1024] E transposed [f][o], zero-padded
#define OFF_HP4    19398656   // float[4][512][1024] split-K partials
#define OFF_TH     27787264   // float[512*1024] tanh(hpre)

__device__ __forceinline__ double retanh_d(double a, double b) {
    // Re(tanh(a+ib)) = sinh(2a)/(cosh(2a)+cos(2b)), stable for large |a|
    if (fabs(a) > 20.0) return a > 0.0 ? 1.0 : -1.0;
    double e2 = exp(2.0 * a);
    double em2 = 1.0 / e2;
    return (e2 - em2) / (e2 + em2 + 2.0 * cos(2.0 * b));
}

// Fused: per-(k,m) weight row sums (bid<192) + W2 transpose (bid>=192)
__global__ void k_misc(const float* __restrict__ w0r, const float* __restrict__ w0i,
                       const float* __restrict__ w1r, const float* __restrict__ w1i,
                       const float* __restrict__ w2r, const float* __restrict__ w2i,
                       const float* __restrict__ w2, char* ws) {
    int bid = blockIdx.x, t = threadIdx.x;
    if (bid < 192) {
        int k = bid >> 6, m = bid & 63;
        const float* wr = (k == 0) ? w0r : (k == 1) ? w1r : w2r;
        const float* wi = (k == 0) ? w0i : (k == 1) ? w1i : w2i;
        double sr = 0.0, si = 0.0;
        for (int c = t; c < MODES; c += 256) {
            sr += (double)wr[m * MODES + c];
            si += (double)wi[m * MODES + c];
        }
        __shared__ double lr[256], li[256];
        lr[t] = sr; li[t] = si; __syncthreads();
        for (int s = 128; s > 0; s >>= 1) {
            if (t < s) { lr[t] += lr[t + s]; li[t] += li[t + s]; }
            __syncthreads();
        }
        if (t == 0) {
            double2* p = (double2*)(ws + OFF_PART);
            p[k * 64 + m] = make_double2(lr[0], li[0]);
        }
    } else {
        int idx = (bid - 192) * 256 + t;
        if (idx < 64 * MODES) {
            int o = idx >> 6, j = idx & 63;
            ((float*)(ws + OFF_W2T))[idx] = w2[j * MODES + o];
        }
    }
}

// c0, c1 totals; T2[j] via 64-point inverse DFT of row sums; gp = g(+1); reset counter.
__global__ void k_prep(char* ws) {
    int t = threadIdx.x; // 64 threads
    double2* part = (double2*)(ws + OFF_PART);
    double* scal  = (double*)(ws + OFF_SCAL);
    double* t2re  = (double*)(ws + OFF_T2RE);
    double* t2im  = (double*)(ws + OFF_T2IM);
    float*  gp    = (float*)(ws + OFF_GP);
    __shared__ double ar[64], ai[64];
    for (int k = 0; k < 2; ++k) {
        double2 v = part[k * 64 + t];
        ar[t] = v.x; ai[t] = v.y; __syncthreads();
        for (int s = 32; s > 0; s >>= 1) {
            if (t < s) { ar[t] += ar[t + s]; ai[t] += ai[t + s]; }
            __syncthreads();
        }
        if (t == 0) { scal[2 * k] = ar[0]; scal[2 * k + 1] = ai[0]; }
        __syncthreads();
    }
    __shared__ double sre[64], sim[64];
    double2 v = part[128 + t];
    sre[t] = v.x; sim[t] = v.y; __syncthreads();
    double tr = 0.0, ti = 0.0;
    for (int m = 0; m < 64; ++m) {
        int r = (t * m) & 63;                  // exact angle reduction
        double th = (double)r * (PI_D / 32.0); // 2*pi*r/64
        double c = cos(th), s = sin(th);
        tr += sre[m] * c - sim[m] * s;
        ti += sre[m] * s + sim[m] * c;
    }
    t2re[t] = tr; t2im[t] = ti;
    gp[t] = (float)retanh_d(tr, ti);
    if (t == 0) *(int*)(ws + OFF_CNT) = 0;
}

// s2 per (b,f) + sign classification + irregular list
__global__ void k_s(const float* __restrict__ params, char* ws) {
    int idx = blockIdx.x * 256 + threadIdx.x; // 512000 total
    const double* scal = (const double*)(ws + OFF_SCAL);
    double c0r = scal[0], c0i = scal[1], c1r = scal[2], c1i = scal[3];
    float p0 = params[(size_t)idx * 64];
    double s1 = retanh_d((double)p0 * c0r, (double)p0 * c0i);
    float s1f = (float)s1;
    double s2 = retanh_d((double)s1f * c1r, (double)s1f * c1i);
    float s2f = (float)s2;
    float sg; bool irr = false;
    if (s2f == 1.0f)       sg = 1.0f;
    else if (s2f == -1.0f) sg = -1.0f;
    else { sg = (s2f >= 0.0f) ? 1.0f : -1.0f; irr = true; }
    ((float*)(ws + OFF_SGN))[idx] = sg;
    ((float*)(ws + OFF_S2))[idx] = s2f;
    if (irr) {
        int pos = atomicAdd((int*)(ws + OFF_CNT), 1);
        ((int*)(ws + OFF_IRR))[pos] = idx;
    }
}

// Transpose sgn [512][1000] -> sgnT [1024][512], zero-pad f>=1000
__global__ void k_trS(char* ws) {
    __shared__ float tile[32][33];
    const float* sgn = (const float*)(ws + OFF_SGN);
    float* sgnT = (float*)(ws + OFF_SGNT);
    int f0 = blockIdx.x * 32, b0 = blockIdx.y * 32;
    int tx = threadIdx.x, ty = threadIdx.y;
#pragma unroll
    for (int i = 0; i < 4; ++i) {
        int b = b0 + ty + i * 8;
        int f = f0 + tx;
        tile[ty + i * 8][tx] = (f < MODES) ? sgn[(size_t)b * MODES + f] : 0.0f;
    }
    __syncthreads();
#pragma unroll
    for (int i = 0; i < 4; ++i) {
        int f = f0 + ty + i * 8;
        int b = b0 + tx;
        sgnT[(size_t)f * 512 + b] = tile[tx][ty + i * 8];
    }
}

// E[o][f] = sum_j gp[j] * W1[o, 64f+j] — coalesced chunk read + 16-lane shuffle reduce
__global__ void k_E(const float* __restrict__ w1, char* ws) {
    int o = blockIdx.y;
    int x = blockIdx.x;
    int t = threadIdx.x; // 512
    const float4* w4 = (const float4*)w1;
    const float4* gp4 = (const float4*)(ws + OFF_GP);
    float4 g = gp4[t & 15];       // (k*512+t)&15 == t&15 since 512 % 16 == 0
    float* E = (float*)(ws + OFF_E);
    size_t rowbase = (size_t)o * 16000;
    int cbase = x * 2048 + t;
#pragma unroll
    for (int k = 0; k < 4; ++k) {
        int gidx = cbase + k * 512;  // float4 index within the row
        float a = 0.0f;
        if (gidx < 16000) {
            float4 v = w4[rowbase + gidx];
            a = v.x * g.x + v.y * g.y + v.z * g.z + v.w * g.w;
        }
        a += __shfl_xor(a, 1);
        a += __shfl_xor(a, 2);
        a += __shfl_xor(a, 4);
        a += __shfl_xor(a, 8);
        if ((t & 15) == 0) {
            int f = x * 128 + k * 32 + (t >> 4);
            if (f < MODES) E[(size_t)o * 1024 + f] = a;
        }
    }
}

// Transpose E [1000][1024] -> ET [1024][1024], zero-pad both dims
__global__ void k_trE(char* ws) {
    __shared__ float tile[32][33];
    const float* E = (const float*)(ws + OFF_E);
    float* ET = (float*)(ws + OFF_ET);
    int f0 = blockIdx.x * 32, o0 = blockIdx.y * 32;
    int tx = threadIdx.x, ty = threadIdx.y;
#pragma unroll
    for (int i = 0; i < 4; ++i) {
        int o = o0 + ty + i * 8;
        int f = f0 + tx;
        tile[ty + i * 8][tx] = (o < MODES && f < MODES) ? E[(size_t)o * 1024 + f] : 0.0f;
    }
    __syncthreads();
#pragma unroll
    for (int i = 0; i < 4; ++i) {
        int f = f0 + ty + i * 8;
        int o = o0 + tx;
        ET[(size_t)f * 1024 + o] = tile[tx][ty + i * 8];
    }
}

// hp4[bz][b][o] = sum_{f in split} sgnT[f][b] * ET[f][o]  — split-K x4, plain stores
__global__ void k_gemm(char* ws) {
    __shared__ float As[32][64]; // [kk][b]
    __shared__ float Bs[32][64]; // [kk][o]
    const float* sgnT = (const float*)(ws + OFF_SGNT);
    const float* ET   = (const float*)(ws + OFF_ET);
    float* hp4        = (float*)(ws + OFF_HP4);
    int bx = blockIdx.x;  // o-tile 0..15
    int by = blockIdx.y;  // b-tile 0..7
    int bz = blockIdx.z;  // split 0..3
    int t = threadIdx.x;  // 256
    int tx = t & 15, ty = t >> 4;
    float acc[4][4] = {};
    int f0base = bz * 256;
    for (int kt = 0; kt < 8; ++kt) {
        int f0 = f0base + kt * 32;
        const float4* srcA = (const float4*)(sgnT + (size_t)f0 * 512 + by * 64);
        const float4* srcB = (const float4*)(ET + (size_t)f0 * 1024 + bx * 64);
        float4* dstA = (float4*)As;
        float4* dstB = (float4*)Bs;
#pragma unroll
        for (int i = 0; i < 2; ++i) {
            int ee = t + i * 256;           // 512 float4 elems per tile
            int row = ee >> 4, col4 = ee & 15;
            dstA[row * 16 + col4] = srcA[(size_t)row * 128 + col4];
            dstB[row * 16 + col4] = srcB[(size_t)row * 256 + col4];
        }
        __syncthreads();
#pragma unroll
        for (int kk = 0; kk < 32; ++kk) {
            float4 a4 = *(const float4*)&As[kk][ty * 4];
            float4 b4 = *(const float4*)&Bs[kk][tx * 4];
            float av[4] = {a4.x, a4.y, a4.z, a4.w};
            float bv[4] = {b4.x, b4.y, b4.z, b4.w};
#pragma unroll
            for (int i = 0; i < 4; ++i)
#pragma unroll
                for (int j = 0; j < 4; ++j) acc[i][j] += av[i] * bv[j];
        }
        __syncthreads();
    }
    size_t zoff = (size_t)bz * 512 * 1024;
#pragma unroll
    for (int i = 0; i < 4; ++i) {
        int b = by * 64 + ty * 4 + i;
        float4 st = make_float4(acc[i][0], acc[i][1], acc[i][2], acc[i][3]);
        *(float4*)&hp4[zoff + (size_t)b * 1024 + bx * 64 + tx * 4] = st;
    }
}

// Exact patch for (b,f) where s2 != +/-1: hp4[0][b,:] += (g(s2) - sgn*gp) . W1[:, 64f:64f+64]
__global__ void k_corr(const float* __restrict__ w1, char* ws) {
    const int t = threadIdx.x;
    int cnt = *(const int*)(ws + OFF_CNT);
    const int* irr    = (const int*)(ws + OFF_IRR);
    const float* s2a  = (const float*)(ws + OFF_S2);
    const float* sgn  = (const float*)(ws + OFF_SGN);
    const double* t2re = (const double*)(ws + OFF_T2RE);
    const double* t2im = (const double*)(ws + OFF_T2IM);
    const float* gp   = (const float*)(ws + OFF_GP);
    float* hp4        = (float*)(ws + OFF_HP4);
    __shared__ __align__(16) float cv[64];
    for (int e = blockIdx.x; e < cnt; e += gridDim.x) {
        int idx = irr[e];
        int b = idx / MODES, f = idx % MODES;
        float s2 = s2a[idx], sg = sgn[idx];
        __syncthreads();
        if (t < 64) {
            double g = retanh_d((double)s2 * t2re[t], (double)s2 * t2im[t]);
            cv[t] = (float)g - sg * gp[t];
        }
        __syncthreads();
        const float4* w4 = (const float4*)w1;
        const float4* c4 = (const float4*)cv;
        for (int o = t; o < MODES; o += 256) {
            size_t base = (size_t)o * 16000 + (size_t)f * 16;
            float acc = 0.0f;
#pragma unroll
            for (int r = 0; r < 16; ++r) {
                float4 w = w4[base + r];
                float4 c = c4[r];
                acc += w.x * c.x + w.y * c.y + w.z * c.z + w.w * c.w;
            }
            atomicAdd(&hp4[(size_t)b * 1024 + o], acc);
        }
    }
}

// th[b][o] = tanhf(b1[o] + sum_z hp4[z][b][o])
__global__ void k_hred(const float* __restrict__ b1, char* ws) {
    int idx = blockIdx.x * 256 + threadIdx.x; // 512*1024
    int o = idx & 1023;
    const float* hp4 = (const float*)(ws + OFF_HP4);
    float s = hp4[idx] + hp4[idx + 524288] + hp4[idx + 2 * 524288] + hp4[idx + 3 * 524288];
    s += (o < MODES) ? b1[o] : 0.0f;
    ((float*)(ws + OFF_TH))[idx] = tanhf(s);
}

// out[b,j] = sigmoid(b2[j] + sum_o th[b][o] * W2t[o][j])
__global__ void k_final(const float* __restrict__ b2, float* __restrict__ out, char* ws) {
    int b = blockIdx.x, t = threadIdx.x;
    const float* thb = (const float*)(ws + OFF_TH);
    const float* w2t = (const float*)(ws + OFF_W2T);
    __shared__ float th[MODES];
    __shared__ float part[4][64];
    for (int o = t; o < MODES; o += 256) th[o] = thb[(size_t)b * 1024 + o];
    __syncthreads();
    int j = t & 63, c = t >> 6;
    float acc = 0.0f;
    for (int o = c * 250; o < c * 250 + 250; ++o) acc += th[o] * w2t[o * 64 + j];
    part[c][j] = acc;
    __syncthreads();
    if (t < 64) {
        float s = part[0][t] + part[1][t] + part[2][t] + part[3][t] + b2[t];
        out[b * 64 + t] = 1.0f / (1.0f + expf(-s));
    }
}

extern "C" void kernel_launch(void* const* d_in, const int* in_sizes, int n_in,
                              void* d_out, int out_size, void* d_ws, size_t ws_size,
                              hipStream_t stream) {
    const float* params = (const float*)d_in[0];
    const float* w0r = (const float*)d_in[1];
    const float* w0i = (const float*)d_in[2];
    const float* w1r = (const float*)d_in[3];
    const float* w1i = (const float*)d_in[4];
    const float* w2r = (const float*)d_in[5];
    const float* w2i = (const float*)d_in[6];
    const float* lin1w = (const float*)d_in[7];
    const float* lin1b = (const float*)d_in[8];
    const float* lin2w = (const float*)d_in[9];
    const float* lin2b = (const float*)d_in[10];
    char* ws = (char*)d_ws;
    float* out = (float*)d_out;

    k_misc<<<442, 256, 0, stream>>>(w0r, w0i, w1r, w1i, w2r, w2i, lin2w, ws);
    k_prep<<<1, 64, 0, stream>>>(ws);
    k_s<<<2000, 256, 0, stream>>>(params, ws);
    k_trS<<<dim3(32, 16), dim3(32, 8), 0, stream>>>(ws);
    k_E<<<dim3(8, 1000), 512, 0, stream>>>(lin1w, ws);
    k_trE<<<dim3(32, 32), dim3(32, 8), 0, stream>>>(ws);
    k_gemm<<<dim3(16, 8, 4), 256, 0, stream>>>(ws);
    k_corr<<<128, 256, 0, stream>>>(lin1w, ws);
    k_hred<<<2048, 256, 0, stream>>>(lin1b, ws);
    k_final<<<512, 256, 0, stream>>>(lin2b, out, ws);
}

// Round 4
// 118.621 us; speedup vs baseline: 2.5778x; 1.1589x over previous
//
#include <hip/hip_runtime.h>
#include <math.h>

#define NB 512
#define MODES 1000
#define LL 64
#define PI_D 3.14159265358979323846

// ws layout (bytes)
#define OFF_PART   0          // double2[192] per-(k,m) weight row sums
#define OFF_SCAL   4096       // double[4]: c0re,c0im,c1re,c1im
#define OFF_T2RE   4224       // double[64]
#define OFF_T2IM   4736       // double[64]
#define OFF_GP     5248       // float[64]  g(+1)
#define OFF_CNT    5504       // int irregular count
#define OFF_W2T    16384      // float[64000]  W2 transposed [o][j]
#define OFF_S2     2621440    // float[512000] s2 value [b*1000+f]
#define OFF_IRR    4718592    // int[512000] irregular indices
#define OFF_E      6815744    // float[1000*1024] E[o][f], f zero-padded to 1024
#define OFF_SGNT   13107200   // float[1024*512]  sgn [f][b] (f>=1000 never read)
#define OFF_HP4    19398656   // float[4][512][1024] split-K partials
#define HP4_STRIDE 524288     // 512*1024

__device__ __forceinline__ double retanh_d(double a, double b) {
    // Re(tanh(a+ib)) = sinh(2a)/(cosh(2a)+cos(2b)), stable for large |a|
    if (fabs(a) > 20.0) return a > 0.0 ? 1.0 : -1.0;
    double e2 = exp(2.0 * a);
    double em2 = 1.0 / e2;
    return (e2 - em2) / (e2 + em2 + 2.0 * cos(2.0 * b));
}

// Per-(weight k, row m) sums of re/im over the 1000 columns. 192 blocks.
__global__ void k_misc(const float* __restrict__ w0r, const float* __restrict__ w0i,
                       const float* __restrict__ w1r, const float* __restrict__ w1i,
                       const float* __restrict__ w2r, const float* __restrict__ w2i,
                       char* ws) {
    int bid = blockIdx.x, t = threadIdx.x;
    int k = bid >> 6, m = bid & 63;
    const float* wr = (k == 0) ? w0r : (k == 1) ? w1r : w2r;
    const float* wi = (k == 0) ? w0i : (k == 1) ? w1i : w2i;
    double sr = 0.0, si = 0.0;
    for (int c = t; c < MODES; c += 256) {
        sr += (double)wr[m * MODES + c];
        si += (double)wi[m * MODES + c];
    }
    __shared__ double lr[256], li[256];
    lr[t] = sr; li[t] = si; __syncthreads();
    for (int s = 128; s > 0; s >>= 1) {
        if (t < s) { lr[t] += lr[t + s]; li[t] += li[t + s]; }
        __syncthreads();
    }
    if (t == 0) {
        double2* p = (double2*)(ws + OFF_PART);
        p[k * 64 + m] = make_double2(lr[0], li[0]);
    }
}

// c0,c1 totals; T2[j] via 64-pt inverse DFT (4-way parallel over m); gp=g(+1); cnt=0.
__global__ void k_prep(char* ws) {
    int t = threadIdx.x;           // 256
    int j = t & 63, q = t >> 6;    // q in 0..3
    double2* part = (double2*)(ws + OFF_PART);
    double* scal  = (double*)(ws + OFF_SCAL);
    double* t2re  = (double*)(ws + OFF_T2RE);
    double* t2im  = (double*)(ws + OFF_T2IM);
    float*  gp    = (float*)(ws + OFF_GP);
    __shared__ double a1[128], a2[128];
    __shared__ double sre[64], sim[64];
    __shared__ double pr[4][64], pi_[4][64];
    if (t < 128) {
        double2 v = part[t];       // k = t>>6, m = t&63
        a1[t] = v.x; a2[t] = v.y;
    }
    if (t < 64) {
        double2 v = part[128 + t];
        sre[t] = v.x; sim[t] = v.y;
    }
    __syncthreads();
    for (int s = 32; s > 0; s >>= 1) {
        if (t < 128 && (t & 63) < s) { a1[t] += a1[t + s]; a2[t] += a2[t + s]; }
        __syncthreads();
    }
    if (t < 2) { scal[2 * t] = a1[t * 64]; scal[2 * t + 1] = a2[t * 64]; }
    // DFT: thread (j,q) sums m = q*16 .. q*16+15
    double tr = 0.0, ti = 0.0;
    for (int mm = q * 16; mm < q * 16 + 16; ++mm) {
        int r = (j * mm) & 63;
        double th = (double)r * (PI_D / 32.0);
        double c = cos(th), s = sin(th);
        tr += sre[mm] * c - sim[mm] * s;
        ti += sre[mm] * s + sim[mm] * c;
    }
    pr[q][j] = tr; pi_[q][j] = ti;
    __syncthreads();
    if (t < 64) {
        double trr = pr[0][t] + pr[1][t] + pr[2][t] + pr[3][t];
        double tii = pi_[0][t] + pi_[1][t] + pi_[2][t] + pi_[3][t];
        t2re[t] = trr; t2im[t] = tii;
        gp[t] = (float)retanh_d(trr, tii);
    }
    if (t == 0) *(int*)(ws + OFF_CNT) = 0;
}

// Fused: E (bid<8000) + s2/sgnT (bid<9000) + W2 transpose (rest). 512 threads.
__global__ void k_sE(const float* __restrict__ w1, const float* __restrict__ params,
                     const float* __restrict__ w2, char* ws) {
    int bid = blockIdx.x, t = threadIdx.x;
    if (bid < 8000) {
        int o = bid >> 3, x = bid & 7;
        const float4* w4 = (const float4*)w1;
        const float4* gp4 = (const float4*)(ws + OFF_GP);
        float4 g = gp4[t & 15];
        float* E = (float*)(ws + OFF_E);
        size_t rowbase = (size_t)o * 16000;
        int cbase = x * 2048 + t;
#pragma unroll
        for (int k = 0; k < 4; ++k) {
            int gidx = cbase + k * 512;
            float a = 0.0f;
            if (gidx < 16000) {
                float4 v = w4[rowbase + gidx];
                a = v.x * g.x + v.y * g.y + v.z * g.z + v.w * g.w;
            }
            a += __shfl_xor(a, 1);
            a += __shfl_xor(a, 2);
            a += __shfl_xor(a, 4);
            a += __shfl_xor(a, 8);
            if ((t & 15) == 0) {
                int f = x * 128 + k * 32 + (t >> 4);  // <= 1023; a==0 for f>=1000
                E[(size_t)o * 1024 + f] = a;
            }
        }
    } else if (bid < 9000) {
        int idx = (bid - 8000) * 512 + t;   // < 512000
        const double* scal = (const double*)(ws + OFF_SCAL);
        double c0r = scal[0], c0i = scal[1], c1r = scal[2], c1i = scal[3];
        float p0 = params[(size_t)idx * 64];
        double s1 = retanh_d((double)p0 * c0r, (double)p0 * c0i);
        float s1f = (float)s1;
        double s2 = retanh_d((double)s1f * c1r, (double)s1f * c1i);
        float s2f = (float)s2;
        float sg; bool irr = false;
        if (s2f == 1.0f)       sg = 1.0f;
        else if (s2f == -1.0f) sg = -1.0f;
        else { sg = (s2f >= 0.0f) ? 1.0f : -1.0f; irr = true; }
        int b = idx / 1000, f = idx - b * 1000;
        ((float*)(ws + OFF_SGNT))[(size_t)f * 512 + b] = sg;
        ((float*)(ws + OFF_S2))[idx] = s2f;
        if (irr) {
            int pos = atomicAdd((int*)(ws + OFF_CNT), 1);
            ((int*)(ws + OFF_IRR))[pos] = idx;
        }
    } else {
        int idx = (bid - 9000) * 512 + t;
        if (idx < 64 * MODES) {
            int o = idx >> 6, j = idx & 63;
            ((float*)(ws + OFF_W2T))[idx] = w2[j * MODES + o];
        }
    }
}

// hp4[bz][b][o] = sum_{f in split} sgnT[f][b] * E[o][f] — B transposed in staging
__global__ void k_gemm(char* ws) {
    __shared__ float As[32][64];   // [kk][b]
    __shared__ float Bs[32][68];   // [kk][o], stride 68 keeps float4 align, 4-way wr conflict
    const float* sgnT = (const float*)(ws + OFF_SGNT);
    const float* E    = (const float*)(ws + OFF_E);
    float* hp4        = (float*)(ws + OFF_HP4);
    int bx = blockIdx.x;  // o-tile 0..15
    int by = blockIdx.y;  // b-tile 0..7
    int bz = blockIdx.z;  // split 0..3
    int t = threadIdx.x;  // 256
    int tx = t & 15, ty = t >> 4;
    float acc[4][4] = {};
    const float4 z4 = make_float4(0.f, 0.f, 0.f, 0.f);
    for (int kt = 0; kt < 8; ++kt) {
        int f0 = bz * 256 + kt * 32;
        // stage A: As[row][col] = sgnT[f0+row][by*64+col], coalesced float4
        float4* dstA = (float4*)As;
#pragma unroll
        for (int i = 0; i < 2; ++i) {
            int ee = t + i * 256;
            int row = ee >> 4, col4 = ee & 15;
            int f = f0 + row;
            float4 v = (f < MODES) ? *(const float4*)(sgnT + (size_t)f * 512 + by * 64 + col4 * 4) : z4;
            dstA[row * 16 + col4] = v;
        }
        // stage B with transpose: Bs[c][r] = E[bx*64+r][f0+c]
#pragma unroll
        for (int p = 0; p < 2; ++p) {
            int r = (t >> 3) + p * 32;   // 0..63
            int c4 = t & 7;
            int o = bx * 64 + r;
            float4 v = (o < MODES) ? *(const float4*)(E + (size_t)o * 1024 + f0 + c4 * 4) : z4;
            Bs[c4 * 4 + 0][r] = v.x;
            Bs[c4 * 4 + 1][r] = v.y;
            Bs[c4 * 4 + 2][r] = v.z;
            Bs[c4 * 4 + 3][r] = v.w;
        }
        __syncthreads();
#pragma unroll
        for (int kk = 0; kk < 32; ++kk) {
            float4 a4 = *(const float4*)&As[kk][ty * 4];
            float4 b4 = *(const float4*)&Bs[kk][tx * 4];
            float av[4] = {a4.x, a4.y, a4.z, a4.w};
            float bv[4] = {b4.x, b4.y, b4.z, b4.w};
#pragma unroll
            for (int i = 0; i < 4; ++i)
#pragma unroll
                for (int j = 0; j < 4; ++j) acc[i][j] += av[i] * bv[j];
        }
        __syncthreads();
    }
    size_t zoff = (size_t)bz * HP4_STRIDE;
#pragma unroll
    for (int i = 0; i < 4; ++i) {
        int b = by * 64 + ty * 4 + i;
        float4 st = make_float4(acc[i][0], acc[i][1], acc[i][2], acc[i][3]);
        *(float4*)&hp4[zoff + (size_t)b * 1024 + bx * 64 + tx * 4] = st;
    }
}

// Fused epilogue: h = sum_z hp4 + b1; rare exact corrections; tanh; dot W2t; sigmoid.
__global__ void k_final(const float* __restrict__ w1, const float* __restrict__ b1,
                        const float* __restrict__ b2, float* __restrict__ out, char* ws) {
    int b = blockIdx.x, t = threadIdx.x;   // 512 blocks x 256
    const float* hp4 = (const float*)(ws + OFF_HP4);
    __shared__ float h[MODES];
    __shared__ float part[4][64];
    __shared__ __align__(16) float cv[64];
    for (int o = t; o < MODES; o += 256) {
        size_t base = (size_t)b * 1024 + o;
        h[o] = hp4[base] + hp4[base + HP4_STRIDE] + hp4[base + 2 * HP4_STRIDE]
             + hp4[base + 3 * HP4_STRIDE] + b1[o];
    }
    __syncthreads();
    int cnt = *(const int*)(ws + OFF_CNT);
    if (cnt > 0) {
        const int* irr     = (const int*)(ws + OFF_IRR);
        const float* s2a   = (const float*)(ws + OFF_S2);
        const float* sgnT  = (const float*)(ws + OFF_SGNT);
        const double* t2re = (const double*)(ws + OFF_T2RE);
        const double* t2im = (const double*)(ws + OFF_T2IM);
        const float* gp    = (const float*)(ws + OFF_GP);
        for (int e = 0; e < cnt; ++e) {
            int idx = irr[e];
            int bb = idx / 1000;
            if (bb != b) continue;              // uniform per block
            int f = idx - bb * 1000;
            float s2 = s2a[idx];
            float sg = sgnT[(size_t)f * 512 + b];
            if (t < 64) {
                double g = retanh_d((double)s2 * t2re[t], (double)s2 * t2im[t]);
                cv[t] = (float)g - sg * gp[t];
            }
            __syncthreads();
            const float4* w4 = (const float4*)w1;
            const float4* c4 = (const float4*)cv;
            for (int o = t; o < MODES; o += 256) {
                size_t base = (size_t)o * 16000 + (size_t)f * 16;
                float a = 0.0f;
#pragma unroll
                for (int r = 0; r < 16; ++r) {
                    float4 w = w4[base + r];
                    float4 c = c4[r];
                    a += w.x * c.x + w.y * c.y + w.z * c.z + w.w * c.w;
                }
                h[o] += a;
            }
            __syncthreads();
        }
    }
    for (int o = t; o < MODES; o += 256) h[o] = tanhf(h[o]);
    __syncthreads();
    const float* w2t = (const float*)(ws + OFF_W2T);
    int j = t & 63, c = t >> 6;
    float acc = 0.0f;
    for (int o = c * 250; o < c * 250 + 250; ++o) acc += h[o] * w2t[o * 64 + j];
    part[c][j] = acc;
    __syncthreads();
    if (t < 64) {
        float s = part[0][t] + part[1][t] + part[2][t] + part[3][t] + b2[t];
        out[b * 64 + t] = 1.0f / (1.0f + expf(-s));
    }
}

extern "C" void kernel_launch(void* const* d_in, const int* in_sizes, int n_in,
                              void* d_out, int out_size, void* d_ws, size_t ws_size,
                              hipStream_t stream) {
    const float* params = (const float*)d_in[0];
    const float* w0r = (const float*)d_in[1];
    const float* w0i = (const float*)d_in[2];
    const float* w1r = (const float*)d_in[3];
    const float* w1i = (const float*)d_in[4];
    const float* w2r = (const float*)d_in[5];
    const float* w2i = (const float*)d_in[6];
    const float* lin1w = (const float*)d_in[7];
    const float* lin1b = (const float*)d_in[8];
    const float* lin2w = (const float*)d_in[9];
    const float* lin2b = (const float*)d_in[10];
    char* ws = (char*)d_ws;
    float* out = (float*)d_out;

    k_misc<<<192, 256, 0, stream>>>(w0r, w0i, w1r, w1i, w2r, w2i, ws);
    k_prep<<<1, 256, 0, stream>>>(ws);
    k_sE<<<9125, 512, 0, stream>>>(lin1w, params, lin2w, ws);
    k_gemm<<<dim3(16, 8, 4), 256, 0, stream>>>(ws);
    k_final<<<512, 256, 0, stream>>>(lin1w, lin1b, lin2b, out, ws);
}

// Round 5
// 116.935 us; speedup vs baseline: 2.6150x; 1.0144x over previous
//
#include <hip/hip_runtime.h>
#include <math.h>

#define NB 512
#define MODES 1000
#define LL 64
#define PI_D 3.14159265358979323846

// ws layout (bytes)
#define OFF_PART   0          // double2[192] per-(k,m) weight row sums
#define OFF_SCAL   4096       // double[4]: c0re,c0im,c1re,c1im
#define OFF_T2RE   4224       // double[64]
#define OFF_T2IM   4736       // double[64]
#define OFF_GP     5248       // float[64]  g(+1)
#define OFF_CNT    5504       // int irregular count
#define OFF_W2T    16384      // float[64000]  W2 transposed [o][j]
#define OFF_S2     2621440    // float[512000] s2 value [b*1000+f]
#define OFF_IRR    4718592    // int[512000] irregular indices
#define OFF_E      6815744    // float[1000*1024] E[o][f], f zero-padded to 1024
#define OFF_SG     13107200   // float[512*1000] sgn [b][f] row-major
#define OFF_HP4    19398656   // float[4][512][1024] split-K partials
#define HP4_STRIDE 524288     // 512*1024

__device__ __forceinline__ double retanh_d(double a, double b) {
    // Re(tanh(a+ib)) = sinh(2a)/(cosh(2a)+cos(2b)), stable for large |a|
    if (fabs(a) > 20.0) return a > 0.0 ? 1.0 : -1.0;
    double e2 = exp(2.0 * a);
    double em2 = 1.0 / e2;
    return (e2 - em2) / (e2 + em2 + 2.0 * cos(2.0 * b));
}

// Per-(weight k, row m) sums of re/im over the 1000 columns. 192 blocks.
__global__ void k_misc(const float* __restrict__ w0r, const float* __restrict__ w0i,
                       const float* __restrict__ w1r, const float* __restrict__ w1i,
                       const float* __restrict__ w2r, const float* __restrict__ w2i,
                       char* ws) {
    int bid = blockIdx.x, t = threadIdx.x;
    int k = bid >> 6, m = bid & 63;
    const float* wr = (k == 0) ? w0r : (k == 1) ? w1r : w2r;
    const float* wi = (k == 0) ? w0i : (k == 1) ? w1i : w2i;
    double sr = 0.0, si = 0.0;
    for (int c = t; c < MODES; c += 256) {
        sr += (double)wr[m * MODES + c];
        si += (double)wi[m * MODES + c];
    }
    __shared__ double lr[256], li[256];
    lr[t] = sr; li[t] = si; __syncthreads();
    for (int s = 128; s > 0; s >>= 1) {
        if (t < s) { lr[t] += lr[t + s]; li[t] += li[t + s]; }
        __syncthreads();
    }
    if (t == 0) {
        double2* p = (double2*)(ws + OFF_PART);
        p[k * 64 + m] = make_double2(lr[0], li[0]);
    }
}

// c0,c1 totals; T2[j] via 64-pt inverse DFT (4-way parallel over m); gp=g(+1); cnt=0.
__global__ void k_prep(char* ws) {
    int t = threadIdx.x;           // 256
    int j = t & 63, q = t >> 6;    // q in 0..3
    double2* part = (double2*)(ws + OFF_PART);
    double* scal  = (double*)(ws + OFF_SCAL);
    double* t2re  = (double*)(ws + OFF_T2RE);
    double* t2im  = (double*)(ws + OFF_T2IM);
    float*  gp    = (float*)(ws + OFF_GP);
    __shared__ double a1[128], a2[128];
    __shared__ double sre[64], sim[64];
    __shared__ double pr[4][64], pi_[4][64];
    if (t < 128) {
        double2 v = part[t];       // k = t>>6, m = t&63
        a1[t] = v.x; a2[t] = v.y;
    }
    if (t < 64) {
        double2 v = part[128 + t];
        sre[t] = v.x; sim[t] = v.y;
    }
    __syncthreads();
    for (int s = 32; s > 0; s >>= 1) {
        if (t < 128 && (t & 63) < s) { a1[t] += a1[t + s]; a2[t] += a2[t + s]; }
        __syncthreads();
    }
    if (t < 2) { scal[2 * t] = a1[t * 64]; scal[2 * t + 1] = a2[t * 64]; }
    // DFT: thread (j,q) sums m = q*16 .. q*16+15
    double tr = 0.0, ti = 0.0;
    for (int mm = q * 16; mm < q * 16 + 16; ++mm) {
        int r = (j * mm) & 63;
        double th = (double)r * (PI_D / 32.0);
        double c = cos(th), s = sin(th);
        tr += sre[mm] * c - sim[mm] * s;
        ti += sre[mm] * s + sim[mm] * c;
    }
    pr[q][j] = tr; pi_[q][j] = ti;
    __syncthreads();
    if (t < 64) {
        double trr = pr[0][t] + pr[1][t] + pr[2][t] + pr[3][t];
        double tii = pi_[0][t] + pi_[1][t] + pi_[2][t] + pi_[3][t];
        t2re[t] = trr; t2im[t] = tii;
        gp[t] = (float)retanh_d(trr, tii);
    }
    if (t == 0) *(int*)(ws + OFF_CNT) = 0;
}

// Fused, ordered so latency-bound work launches first and hides under the E-stream:
//   bid < 125          : W2 transpose
//   125 <= bid < 1125  : s2/sgn per (b,f)
//   1125 <= bid < 9125 : E[o][f] = sum_j gp[j]*W1[o,64f+j]  (256 MB stream)
__global__ void k_sE(const float* __restrict__ w1, const float* __restrict__ params,
                     const float* __restrict__ w2, char* ws) {
    int bid = blockIdx.x, t = threadIdx.x;
    if (bid < 125) {
        int idx = bid * 512 + t;   // < 64000
        int o = idx >> 6, j = idx & 63;
        ((float*)(ws + OFF_W2T))[idx] = w2[j * MODES + o];
    } else if (bid < 1125) {
        int idx = (bid - 125) * 512 + t;   // < 512000
        const double* scal = (const double*)(ws + OFF_SCAL);
        double c0r = scal[0], c0i = scal[1], c1r = scal[2], c1i = scal[3];
        float p0 = params[(size_t)idx * 64];
        double s1 = retanh_d((double)p0 * c0r, (double)p0 * c0i);
        float s1f = (float)s1;
        double s2 = retanh_d((double)s1f * c1r, (double)s1f * c1i);
        float s2f = (float)s2;
        float sg; bool irr = false;
        if (s2f == 1.0f)       sg = 1.0f;
        else if (s2f == -1.0f) sg = -1.0f;
        else { sg = (s2f >= 0.0f) ? 1.0f : -1.0f; irr = true; }
        ((float*)(ws + OFF_SG))[idx] = sg;     // coalesced [b][f]
        ((float*)(ws + OFF_S2))[idx] = s2f;
        if (irr) {
            int pos = atomicAdd((int*)(ws + OFF_CNT), 1);
            ((int*)(ws + OFF_IRR))[pos] = idx;
        }
    } else {
        int e = bid - 1125;
        int o = e >> 3, x = e & 7;
        const float4* w4 = (const float4*)w1;
        const float4* gp4 = (const float4*)(ws + OFF_GP);
        float4 g = gp4[t & 15];
        float* E = (float*)(ws + OFF_E);
        size_t rowbase = (size_t)o * 16000;
        int cbase = x * 2048 + t;
#pragma unroll
        for (int k = 0; k < 4; ++k) {
            int gidx = cbase + k * 512;
            float a = 0.0f;
            if (gidx < 16000) {
                float4 v = w4[rowbase + gidx];
                a = v.x * g.x + v.y * g.y + v.z * g.z + v.w * g.w;
            }
            a += __shfl_xor(a, 1);
            a += __shfl_xor(a, 2);
            a += __shfl_xor(a, 4);
            a += __shfl_xor(a, 8);
            if ((t & 15) == 0) {
                int f = x * 128 + k * 32 + (t >> 4);  // <= 1023; a==0 for f>=1000
                E[(size_t)o * 1024 + f] = a;
            }
        }
    }
}

// hp4[bz][b][o] = sum_{f in split} sgn[b][f] * E[o][f] — both tiles transposed in staging
__global__ void k_gemm(char* ws) {
    __shared__ float As[32][68];   // [kk][b]
    __shared__ float Bs[32][68];   // [kk][o]
    const float* sgn = (const float*)(ws + OFF_SG);
    const float* E   = (const float*)(ws + OFF_E);
    float* hp4       = (float*)(ws + OFF_HP4);
    int bx = blockIdx.x;  // o-tile 0..15
    int by = blockIdx.y;  // b-tile 0..7
    int bz = blockIdx.z;  // split 0..3
    int t = threadIdx.x;  // 256
    int tx = t & 15, ty = t >> 4;
    float acc[4][4] = {};
    const float4 z4 = make_float4(0.f, 0.f, 0.f, 0.f);
    for (int kt = 0; kt < 8; ++kt) {
        int f0 = bz * 256 + kt * 32;
        // stage A with transpose: As[c][r] = sgn[by*64+r][f0+c]
#pragma unroll
        for (int p = 0; p < 2; ++p) {
            int r = (t >> 3) + p * 32;   // 0..63
            int c4 = t & 7;
            int f = f0 + c4 * 4;
            float4 v = (f < MODES) ? *(const float4*)(sgn + (size_t)(by * 64 + r) * MODES + f) : z4;
            As[c4 * 4 + 0][r] = v.x;
            As[c4 * 4 + 1][r] = v.y;
            As[c4 * 4 + 2][r] = v.z;
            As[c4 * 4 + 3][r] = v.w;
        }
        // stage B with transpose: Bs[c][r] = E[bx*64+r][f0+c]
#pragma unroll
        for (int p = 0; p < 2; ++p) {
            int r = (t >> 3) + p * 32;   // 0..63
            int c4 = t & 7;
            int o = bx * 64 + r;
            float4 v = (o < MODES) ? *(const float4*)(E + (size_t)o * 1024 + f0 + c4 * 4) : z4;
            Bs[c4 * 4 + 0][r] = v.x;
            Bs[c4 * 4 + 1][r] = v.y;
            Bs[c4 * 4 + 2][r] = v.z;
            Bs[c4 * 4 + 3][r] = v.w;
        }
        __syncthreads();
#pragma unroll
        for (int kk = 0; kk < 32; ++kk) {
            float4 a4 = *(const float4*)&As[kk][ty * 4];
            float4 b4 = *(const float4*)&Bs[kk][tx * 4];
            float av[4] = {a4.x, a4.y, a4.z, a4.w};
            float bv[4] = {b4.x, b4.y, b4.z, b4.w};
#pragma unroll
            for (int i = 0; i < 4; ++i)
#pragma unroll
                for (int j = 0; j < 4; ++j) acc[i][j] += av[i] * bv[j];
        }
        __syncthreads();
    }
    size_t zoff = (size_t)bz * HP4_STRIDE;
#pragma unroll
    for (int i = 0; i < 4; ++i) {
        int b = by * 64 + ty * 4 + i;
        float4 st = make_float4(acc[i][0], acc[i][1], acc[i][2], acc[i][3]);
        *(float4*)&hp4[zoff + (size_t)b * 1024 + bx * 64 + tx * 4] = st;
    }
}

// Fused epilogue: h = sum_z hp4 + b1; rare exact corrections; tanh; dot W2t; sigmoid.
__global__ void k_final(const float* __restrict__ w1, const float* __restrict__ b1,
                        const float* __restrict__ b2, float* __restrict__ out, char* ws) {
    int b = blockIdx.x, t = threadIdx.x;   // 512 blocks x 256
    const float* hp4 = (const float*)(ws + OFF_HP4);
    __shared__ float h[MODES];
    __shared__ float part[4][64];
    __shared__ __align__(16) float cv[64];
    for (int o = t; o < MODES; o += 256) {
        size_t base = (size_t)b * 1024 + o;
        h[o] = hp4[base] + hp4[base + HP4_STRIDE] + hp4[base + 2 * HP4_STRIDE]
             + hp4[base + 3 * HP4_STRIDE] + b1[o];
    }
    __syncthreads();
    int cnt = *(const int*)(ws + OFF_CNT);
    if (cnt > 0) {
        const int* irr     = (const int*)(ws + OFF_IRR);
        const float* s2a   = (const float*)(ws + OFF_S2);
        const float* sgn   = (const float*)(ws + OFF_SG);
        const double* t2re = (const double*)(ws + OFF_T2RE);
        const double* t2im = (const double*)(ws + OFF_T2IM);
        const float* gp    = (const float*)(ws + OFF_GP);
        for (int e = 0; e < cnt; ++e) {
            int idx = irr[e];
            int bb = idx / 1000;
            if (bb != b) continue;              // uniform per block
            int f = idx - bb * 1000;
            float s2 = s2a[idx];
            float sg = sgn[idx];
            if (t < 64) {
                double g = retanh_d((double)s2 * t2re[t], (double)s2 * t2im[t]);
                cv[t] = (float)g - sg * gp[t];
            }
            __syncthreads();
            const float4* w4 = (const float4*)w1;
            const float4* c4 = (const float4*)cv;
            for (int o = t; o < MODES; o += 256) {
                size_t base = (size_t)o * 16000 + (size_t)f * 16;
                float a = 0.0f;
#pragma unroll
                for (int r = 0; r < 16; ++r) {
                    float4 w = w4[base + r];
                    float4 c = c4[r];
                    a += w.x * c.x + w.y * c.y + w.z * c.z + w.w * c.w;
                }
                h[o] += a;
            }
            __syncthreads();
        }
    }
    for (int o = t; o < MODES; o += 256) h[o] = tanhf(h[o]);
    __syncthreads();
    const float* w2t = (const float*)(ws + OFF_W2T);
    int j = t & 63, c = t >> 6;
    float acc = 0.0f;
    for (int o = c * 250; o < c * 250 + 250; ++o) acc += h[o] * w2t[o * 64 + j];
    part[c][j] = acc;
    __syncthreads();
    if (t < 64) {
        float s = part[0][t] + part[1][t] + part[2][t] + part[3][t] + b2[t];
        out[b * 64 + t] = 1.0f / (1.0f + expf(-s));
    }
}

extern "C" void kernel_launch(void* const* d_in, const int* in_sizes, int n_in,
                              void* d_out, int out_size, void* d_ws, size_t ws_size,
                              hipStream_t stream) {
    const float* params = (const float*)d_in[0];
    const float* w0r = (const float*)d_in[1];
    const float* w0i = (const float*)d_in[2];
    const float* w1r = (const float*)d_in[3];
    const float* w1i = (const float*)d_in[4];
    const float* w2r = (const float*)d_in[5];
    const float* w2i = (const float*)d_in[6];
    const float* lin1w = (const float*)d_in[7];
    const float* lin1b = (const float*)d_in[8];
    const float* lin2w = (const float*)d_in[9];
    const float* lin2b = (const float*)d_in[10];
    char* ws = (char*)d_ws;
    float* out = (float*)d_out;

    k_misc<<<192, 256, 0, stream>>>(w0r, w0i, w1r, w1i, w2r, w2i, ws);
    k_prep<<<1, 256, 0, stream>>>(ws);
    k_sE<<<9125, 512, 0, stream>>>(lin1w, params, lin2w, ws);
    k_gemm<<<dim3(16, 8, 4), 256, 0, stream>>>(ws);
    k_final<<<512, 256, 0, stream>>>(lin1w, lin1b, lin2b, out, ws);
}

// Round 6
// 112.868 us; speedup vs baseline: 2.7092x; 1.0360x over previous
//
#include <hip/hip_runtime.h>
#include <math.h>

#define NB 512
#define MODES 1000
#define LL 64
#define PI_D 3.14159265358979323846

// ws layout (bytes)
#define OFF_PART   0          // double2[192] per-(k,m) weight row sums
#define OFF_SCAL   4096       // double[4]: c0re,c0im,c1re,c1im
#define OFF_T2RE   4224       // double[64]
#define OFF_T2IM   4736       // double[64]
#define OFF_GP     5248       // float[64]  g(+1)
#define OFF_CNT    5504       // int irregular count
#define OFF_W2T    16384      // float[64000]  W2 transposed [o][j]
#define OFF_S2     2621440    // float[512000] s2 value [b*1000+f]
#define OFF_IRR    4718592    // int[512000] irregular indices
#define OFF_E      6815744    // float[1000*1024] E[o][f], f zero-padded to 1024
#define OFF_SG     13107200   // float[512*1000] sgn [b][f] row-major
#define OFF_HP4    19398656   // float[4][512][1024] split-K partials
#define OFF_P0C    27787264   // float[512000] compacted params[...,0]
#define HP4_STRIDE 524288     // 512*1024

__device__ __forceinline__ double retanh_d(double a, double b) {
    // Re(tanh(a+ib)) = sinh(2a)/(cosh(2a)+cos(2b)), stable for large |a|
    if (fabs(a) > 20.0) return a > 0.0 ? 1.0 : -1.0;
    double e2 = exp(2.0 * a);
    double em2 = 1.0 / e2;
    return (e2 - em2) / (e2 + em2 + 2.0 * cos(2.0 * b));
}

// Fused independent preamble work:
//   bid < 192   : per-(k,m) weight row sums -> part[]
//   192..441    : W2 transpose -> w2t
//   442..2441   : params[...,0] compaction -> p0c
__global__ void k_misc(const float* __restrict__ w0r, const float* __restrict__ w0i,
                       const float* __restrict__ w1r, const float* __restrict__ w1i,
                       const float* __restrict__ w2r, const float* __restrict__ w2i,
                       const float* __restrict__ w2, const float* __restrict__ params,
                       char* ws) {
    int bid = blockIdx.x, t = threadIdx.x;
    if (bid < 192) {
        int k = bid >> 6, m = bid & 63;
        const float* wr = (k == 0) ? w0r : (k == 1) ? w1r : w2r;
        const float* wi = (k == 0) ? w0i : (k == 1) ? w1i : w2i;
        double sr = 0.0, si = 0.0;
        for (int c = t; c < MODES; c += 256) {
            sr += (double)wr[m * MODES + c];
            si += (double)wi[m * MODES + c];
        }
        __shared__ double lr[256], li[256];
        lr[t] = sr; li[t] = si; __syncthreads();
        for (int s = 128; s > 0; s >>= 1) {
            if (t < s) { lr[t] += lr[t + s]; li[t] += li[t + s]; }
            __syncthreads();
        }
        if (t == 0) {
            double2* p = (double2*)(ws + OFF_PART);
            p[k * 64 + m] = make_double2(lr[0], li[0]);
        }
    } else if (bid < 442) {
        int idx = (bid - 192) * 256 + t;   // < 64000
        int o = idx >> 6, j = idx & 63;
        ((float*)(ws + OFF_W2T))[idx] = w2[j * MODES + o];
    } else {
        int idx = (bid - 442) * 256 + t;   // < 512000
        ((float*)(ws + OFF_P0C))[idx] = params[(size_t)idx * 64];
    }
}

// c0,c1 totals; T2 via 64-pt inverse DFT with LDS twiddle table (64 sincos total);
// gp = g(+1); cnt = 0.
__global__ void k_prep(char* ws) {
    int t = threadIdx.x;           // 256
    int j = t & 63, q = t >> 6;    // q in 0..3
    double2* part = (double2*)(ws + OFF_PART);
    double* scal  = (double*)(ws + OFF_SCAL);
    double* t2re  = (double*)(ws + OFF_T2RE);
    double* t2im  = (double*)(ws + OFF_T2IM);
    float*  gp    = (float*)(ws + OFF_GP);
    __shared__ double a1[128], a2[128];
    __shared__ double sre[64], sim[64];
    __shared__ double tc[64], tsn[64];
    __shared__ double pr[4][64], pi_[4][64];
    if (t < 128) {
        double2 v = part[t];       // k = t>>6, m = t&63
        a1[t] = v.x; a2[t] = v.y;
    }
    if (t < 64) {
        double2 v = part[128 + t];
        sre[t] = v.x; sim[t] = v.y;
    }
    if (t >= 128 && t < 192) {     // twiddle table: one sincos per lane
        int r = t - 128;
        double s, c;
        sincos((double)r * (PI_D / 32.0), &s, &c);
        tc[r] = c; tsn[r] = s;
    }
    __syncthreads();
    for (int s = 32; s > 0; s >>= 1) {
        if (t < 128 && (t & 63) < s) { a1[t] += a1[t + s]; a2[t] += a2[t + s]; }
        __syncthreads();
    }
    if (t < 2) { scal[2 * t] = a1[t * 64]; scal[2 * t + 1] = a2[t * 64]; }
    // DFT: thread (j,q) sums m = q*16 .. q*16+15 using the table
    double tr = 0.0, ti = 0.0;
    for (int mm = q * 16; mm < q * 16 + 16; ++mm) {
        int r = (j * mm) & 63;
        double c = tc[r], s = tsn[r];
        tr += sre[mm] * c - sim[mm] * s;
        ti += sre[mm] * s + sim[mm] * c;
    }
    pr[q][j] = tr; pi_[q][j] = ti;
    __syncthreads();
    if (t < 64) {
        double trr = pr[0][t] + pr[1][t] + pr[2][t] + pr[3][t];
        double tii = pi_[0][t] + pi_[1][t] + pi_[2][t] + pi_[3][t];
        t2re[t] = trr; t2im[t] = tii;
        gp[t] = (float)retanh_d(trr, tii);
    }
    if (t == 0) *(int*)(ws + OFF_CNT) = 0;
}

// Fused: s2/sgn (bid<1000, reads compact p0c) then E-stream (256 MB of W1).
__global__ void k_sE(const float* __restrict__ w1, char* ws) {
    int bid = blockIdx.x, t = threadIdx.x;
    if (bid < 1000) {
        int idx = bid * 512 + t;   // < 512000
        const double* scal = (const double*)(ws + OFF_SCAL);
        double c0r = scal[0], c0i = scal[1], c1r = scal[2], c1i = scal[3];
        float p0 = ((const float*)(ws + OFF_P0C))[idx];
        double s1 = retanh_d((double)p0 * c0r, (double)p0 * c0i);
        float s1f = (float)s1;
        double s2 = retanh_d((double)s1f * c1r, (double)s1f * c1i);
        float s2f = (float)s2;
        float sg; bool irr = false;
        if (s2f == 1.0f)       sg = 1.0f;
        else if (s2f == -1.0f) sg = -1.0f;
        else { sg = (s2f >= 0.0f) ? 1.0f : -1.0f; irr = true; }
        ((float*)(ws + OFF_SG))[idx] = sg;     // coalesced [b][f]
        ((float*)(ws + OFF_S2))[idx] = s2f;
        if (irr) {
            int pos = atomicAdd((int*)(ws + OFF_CNT), 1);
            ((int*)(ws + OFF_IRR))[pos] = idx;
        }
    } else {
        int e = bid - 1000;
        int o = e >> 3, x = e & 7;
        const float4* w4 = (const float4*)w1;
        const float4* gp4 = (const float4*)(ws + OFF_GP);
        float4 g = gp4[t & 15];
        float* E = (float*)(ws + OFF_E);
        size_t rowbase = (size_t)o * 16000;
        int cbase = x * 2048 + t;
#pragma unroll
        for (int k = 0; k < 4; ++k) {
            int gidx = cbase + k * 512;
            float a = 0.0f;
            if (gidx < 16000) {
                float4 v = w4[rowbase + gidx];
                a = v.x * g.x + v.y * g.y + v.z * g.z + v.w * g.w;
            }
            a += __shfl_xor(a, 1);
            a += __shfl_xor(a, 2);
            a += __shfl_xor(a, 4);
            a += __shfl_xor(a, 8);
            if ((t & 15) == 0) {
                int f = x * 128 + k * 32 + (t >> 4);  // <= 1023; a==0 for f>=1000
                E[(size_t)o * 1024 + f] = a;
            }
        }
    }
}

// hp4[bz][b][o] = sum_{f in split} sgn[b][f] * E[o][f] — both tiles transposed in staging
__global__ void k_gemm(char* ws) {
    __shared__ float As[32][68];   // [kk][b]
    __shared__ float Bs[32][68];   // [kk][o]
    const float* sgn = (const float*)(ws + OFF_SG);
    const float* E   = (const float*)(ws + OFF_E);
    float* hp4       = (float*)(ws + OFF_HP4);
    int bx = blockIdx.x;  // o-tile 0..15
    int by = blockIdx.y;  // b-tile 0..7
    int bz = blockIdx.z;  // split 0..3
    int t = threadIdx.x;  // 256
    int tx = t & 15, ty = t >> 4;
    float acc[4][4] = {};
    const float4 z4 = make_float4(0.f, 0.f, 0.f, 0.f);
    for (int kt = 0; kt < 8; ++kt) {
        int f0 = bz * 256 + kt * 32;
        // stage A with transpose: As[c][r] = sgn[by*64+r][f0+c]
#pragma unroll
        for (int p = 0; p < 2; ++p) {
            int r = (t >> 3) + p * 32;   // 0..63
            int c4 = t & 7;
            int f = f0 + c4 * 4;
            float4 v = (f < MODES) ? *(const float4*)(sgn + (size_t)(by * 64 + r) * MODES + f) : z4;
            As[c4 * 4 + 0][r] = v.x;
            As[c4 * 4 + 1][r] = v.y;
            As[c4 * 4 + 2][r] = v.z;
            As[c4 * 4 + 3][r] = v.w;
        }
        // stage B with transpose: Bs[c][r] = E[bx*64+r][f0+c]
#pragma unroll
        for (int p = 0; p < 2; ++p) {
            int r = (t >> 3) + p * 32;   // 0..63
            int c4 = t & 7;
            int o = bx * 64 + r;
            float4 v = (o < MODES) ? *(const float4*)(E + (size_t)o * 1024 + f0 + c4 * 4) : z4;
            Bs[c4 * 4 + 0][r] = v.x;
            Bs[c4 * 4 + 1][r] = v.y;
            Bs[c4 * 4 + 2][r] = v.z;
            Bs[c4 * 4 + 3][r] = v.w;
        }
        __syncthreads();
#pragma unroll
        for (int kk = 0; kk < 32; ++kk) {
            float4 a4 = *(const float4*)&As[kk][ty * 4];
            float4 b4 = *(const float4*)&Bs[kk][tx * 4];
            float av[4] = {a4.x, a4.y, a4.z, a4.w};
            float bv[4] = {b4.x, b4.y, b4.z, b4.w};
#pragma unroll
            for (int i = 0; i < 4; ++i)
#pragma unroll
                for (int j = 0; j < 4; ++j) acc[i][j] += av[i] * bv[j];
        }
        __syncthreads();
    }
    size_t zoff = (size_t)bz * HP4_STRIDE;
#pragma unroll
    for (int i = 0; i < 4; ++i) {
        int b = by * 64 + ty * 4 + i;
        float4 st = make_float4(acc[i][0], acc[i][1], acc[i][2], acc[i][3]);
        *(float4*)&hp4[zoff + (size_t)b * 1024 + bx * 64 + tx * 4] = st;
    }
}

// Fused epilogue: h = sum_z hp4 + b1; rare exact corrections; tanh; dot W2t; sigmoid.
__global__ void k_final(const float* __restrict__ w1, const float* __restrict__ b1,
                        const float* __restrict__ b2, float* __restrict__ out, char* ws) {
    int b = blockIdx.x, t = threadIdx.x;   // 512 blocks x 256
    const float* hp4 = (const float*)(ws + OFF_HP4);
    __shared__ float h[MODES];
    __shared__ float part[4][64];
    __shared__ __align__(16) float cv[64];
    for (int o = t; o < MODES; o += 256) {
        size_t base = (size_t)b * 1024 + o;
        h[o] = hp4[base] + hp4[base + HP4_STRIDE] + hp4[base + 2 * HP4_STRIDE]
             + hp4[base + 3 * HP4_STRIDE] + b1[o];
    }
    __syncthreads();
    int cnt = *(const int*)(ws + OFF_CNT);
    if (cnt > 0) {
        const int* irr     = (const int*)(ws + OFF_IRR);
        const float* s2a   = (const float*)(ws + OFF_S2);
        const float* sgn   = (const float*)(ws + OFF_SG);
        const double* t2re = (const double*)(ws + OFF_T2RE);
        const double* t2im = (const double*)(ws + OFF_T2IM);
        const float* gp    = (const float*)(ws + OFF_GP);
        for (int e = 0; e < cnt; ++e) {
            int idx = irr[e];
            int bb = idx / 1000;
            if (bb != b) continue;              // uniform per block
            int f = idx - bb * 1000;
            float s2 = s2a[idx];
            float sg = sgn[idx];
            if (t < 64) {
                double g = retanh_d((double)s2 * t2re[t], (double)s2 * t2im[t]);
                cv[t] = (float)g - sg * gp[t];
            }
            __syncthreads();
            const float4* w4 = (const float4*)w1;
            const float4* c4 = (const float4*)cv;
            for (int o = t; o < MODES; o += 256) {
                size_t base = (size_t)o * 16000 + (size_t)f * 16;
                float a = 0.0f;
#pragma unroll
                for (int r = 0; r < 16; ++r) {
                    float4 w = w4[base + r];
                    float4 c = c4[r];
                    a += w.x * c.x + w.y * c.y + w.z * c.z + w.w * c.w;
                }
                h[o] += a;
            }
            __syncthreads();
        }
    }
    for (int o = t; o < MODES; o += 256) h[o] = tanhf(h[o]);
    __syncthreads();
    const float* w2t = (const float*)(ws + OFF_W2T);
    int j = t & 63, c = t >> 6;
    float acc = 0.0f;
    for (int o = c * 250; o < c * 250 + 250; ++o) acc += h[o] * w2t[o * 64 + j];
    part[c][j] = acc;
    __syncthreads();
    if (t < 64) {
        float s = part[0][t] + part[1][t] + part[2][t] + part[3][t] + b2[t];
        out[b * 64 + t] = 1.0f / (1.0f + expf(-s));
    }
}

extern "C" void kernel_launch(void* const* d_in, const int* in_sizes, int n_in,
                              void* d_out, int out_size, void* d_ws, size_t ws_size,
                              hipStream_t stream) {
    const float* params = (const float*)d_in[0];
    const float* w0r = (const float*)d_in[1];
    const float* w0i = (const float*)d_in[2];
    const float* w1r = (const float*)d_in[3];
    const float* w1i = (const float*)d_in[4];
    const float* w2r = (const float*)d_in[5];
    const float* w2i = (const float*)d_in[6];
    const float* lin1w = (const float*)d_in[7];
    const float* lin1b = (const float*)d_in[8];
    const float* lin2w = (const float*)d_in[9];
    const float* lin2b = (const float*)d_in[10];
    char* ws = (char*)d_ws;
    float* out = (float*)d_out;

    k_misc<<<2442, 256, 0, stream>>>(w0r, w0i, w1r, w1i, w2r, w2i, lin2w, params, ws);
    k_prep<<<1, 256, 0, stream>>>(ws);
    k_sE<<<9000, 512, 0, stream>>>(lin1w, ws);
    k_gemm<<<dim3(16, 8, 4), 256, 0, stream>>>(ws);
    k_final<<<512, 256, 0, stream>>>(lin1w, lin1b, lin2b, out, ws);
}